// Round 6
// baseline (665.467 us; speedup 1.0000x reference)
//
#include <hip/hip_runtime.h>

#define BB 8
#define CC 256
#define TT 4
#define NNv 4096
#define HH 1024
#define LLv (TT*NNv)   // 16384

typedef int   int4v __attribute__((ext_vector_type(4)));
typedef float f32x4 __attribute__((ext_vector_type(4)));

// ---- fc1 weights -> 3 signed radix-256 i8 digits, MFMA-fragment-linear ----
// w = (d0*2^16 + d1*2^8 + d2) * 2^-24 exactly. Frag block per (d, ht64, ko, gg):
// 64 lanes x 16B; lane = q*16 + (h&15); byte j = c&15; k = ko*64 + q*16 + j.
// (mapping verified end-to-end by the R3 i8 kernel, absmax 2e-3)
__global__ __launch_bounds__(256) void k_prep1(const float* __restrict__ w,
                                               unsigned char* __restrict__ wd)
{
    int i = blockIdx.x * 256 + threadIdx.x;        // i = h*256 + c
    int h = i >> 8, c = i & 255;
    int w24 = __float2int_rn(w[i] * 16777216.0f);
    int d2 = ((w24 + 128) & 255) - 128;  w24 = (w24 - d2) >> 8;
    int d1 = ((w24 + 128) & 255) - 128;  w24 = (w24 - d1) >> 8;
    int d0 = w24;                                   // |d0| small for |w|<0.3
    size_t off = ((((size_t)(h >> 6) * 4 + (c >> 6)) * 4 + ((h >> 4) & 3)) << 10)
               + ((c >> 4) & 3) * 256 + (h & 15) * 16 + (c & 15);
    wd[off] = (unsigned char)d0;
    wd[262144 + off] = (unsigned char)d1;
    wd[2 * 262144 + off] = (unsigned char)d2;
}

// ---- fc2 weights -> 2 signed radix-256 i8 digits ----
// w = (d0*2^8 + d1) * 2^-16. Frag block per (d, ct, ko2, cg): 64 lanes x 16B,
// lane = q*16 + (c&15), byte j = h&15, k(h) = ko2*64 + q*16 + j.
__global__ __launch_bounds__(256) void k_prep2(const float* __restrict__ w,
                                               unsigned char* __restrict__ wd)
{
    int i = blockIdx.x * 256 + threadIdx.x;        // i = c*1024 + h
    int c = i >> 10, h = i & 1023;
    int w16 = __float2int_rn(w[i] * 65536.0f);
    int d1 = ((w16 + 128) & 255) - 128;  w16 = (w16 - d1) >> 8;
    int d0 = w16;
    size_t off = ((((size_t)(c >> 6) * 16 + (h >> 6)) * 4 + ((c >> 4) & 3)) << 10)
               + ((h >> 4) & 3) * 256 + (c & 15) * 16 + (h & 15);
    wd[off] = (unsigned char)d0;
    wd[262144 + off] = (unsigned char)d1;
}

// ---- bn2 + LIF over T + transpose: x[b][c][t][n] -> s1T[bl][t][n][c] bytes ----
__global__ __launch_bounds__(256) void k_bn2_lif_t(
    const float* __restrict__ x,
    const float* __restrict__ g, const float* __restrict__ be,
    const float* __restrict__ mu, const float* __restrict__ va,
    unsigned char* __restrict__ s1T, int b0)
{
    __shared__ unsigned char ts[TT][64][80];       // [t][c][n], stride 80 (16B-aligned)
    int tx = threadIdx.x;
    int n0 = blockIdx.x * 64;
    int c0 = blockIdx.y * 64;
    int bl = blockIdx.z;
    int b  = b0 + bl;
    int cl = tx >> 2, np = tx & 3;
    int c = c0 + cl;
    float rsq = __fdiv_rn(1.0f, __fsqrt_rn(__fadd_rn(va[c], 1e-5f)));
    float inv = __fmul_rn(g[c], rsq);
    float add = __fsub_rn(be[c], __fmul_rn(mu[c], inv));
    size_t xb = ((size_t)(b * CC + c) * TT) * NNv + n0 + np * 16;
    float v[16];
    #pragma unroll
    for (int i = 0; i < 16; i++) v[i] = 0.0f;
    #pragma unroll
    for (int t = 0; t < TT; t++) {
        float4 p[4];
        #pragma unroll
        for (int k = 0; k < 4; k++) p[k] = *(const float4*)(x + xb + (size_t)t * NNv + 4 * k);
        const float* xp = (const float*)p;
        unsigned int ob[4] = {0, 0, 0, 0};
        #pragma unroll
        for (int i = 0; i < 16; i++) {
            float y = __fadd_rn(__fmul_rn(xp[i], inv), add);
            float vv = __fadd_rn(v[i], __fdiv_rn(__fsub_rn(y, v[i]), 1.5f));
            bool sp = vv >= 1.0f;
            v[i] = sp ? 0.0f : vv;
            if (sp) ob[i >> 2] |= 1u << (8 * (i & 3));
        }
        uint4 pk; pk.x = ob[0]; pk.y = ob[1]; pk.z = ob[2]; pk.w = ob[3];
        *(uint4*)&ts[t][cl][np * 16] = pk;
    }
    __syncthreads();
    int nl = tx >> 2, cp = tx & 3;
    #pragma unroll
    for (int t = 0; t < TT; t++) {
        unsigned int u[4];
        #pragma unroll
        for (int kk = 0; kk < 4; kk++) {
            u[kk] = (unsigned int)ts[t][cp * 16 + kk * 4 + 0][nl]
                  | ((unsigned int)ts[t][cp * 16 + kk * 4 + 1][nl] << 8)
                  | ((unsigned int)ts[t][cp * 16 + kk * 4 + 2][nl] << 16)
                  | ((unsigned int)ts[t][cp * 16 + kk * 4 + 3][nl] << 24);
        }
        uint4 pk; pk.x = u[0]; pk.y = u[1]; pk.z = u[2]; pk.w = u[3];
        *(uint4*)(s1T + ((size_t)(bl * TT + t) * NNv + n0 + nl) * CC + c0 + cp * 16) = pk;
    }
}

// ------- GEMM1 (fc1) i8 3-digit with acc<<8 shift trick, fused bn1+LIF -------
// Tile 64h x 64n x 4t (proven-cache geometry); spikes staged ONCE (64KB LDS,
// XOR-swizzled), single barrier; digit-major passes, exact integer combine.
__global__ __launch_bounds__(256, 3) void k_gemm1_lif(
    const unsigned char* __restrict__ w1d,
    const float* __restrict__ b1,
    const float* __restrict__ g1, const float* __restrict__ be1,
    const float* __restrict__ mu1, const float* __restrict__ va1,
    const unsigned char* __restrict__ s1T, unsigned char* __restrict__ s2T)
{
    __shared__ unsigned char Ls[TT * 64 * 256];    // 64KB: [row=t*64+n][slot16^swz]
    const int tx = threadIdx.x;
    const int n0 = blockIdx.x * 64;
    const int ht = blockIdx.y;                     // h0 = ht*64
    const int bl = blockIdx.z;
    const int lane = tx & 63, w = tx >> 6;
    const int q = lane >> 4, ln = lane & 15;
    const int mh = (w & 1) * 32, wn = (w >> 1) * 32;
    const int h0 = ht * 64;

    // --- stage all spikes once: LDS[row][slot^(row&15)] = s1T[row][slot] ---
    #pragma unroll
    for (int half = 0; half < 2; half++) {
        uint4 st[8];
        #pragma unroll
        for (int k = 0; k < 8; k++) {
            int id = (half * 8 + k) * 256 + tx;
            int row = id >> 4, slot = id & 15;
            st[k] = *(const uint4*)(s1T + ((size_t)(bl * TT + (row >> 6)) * NNv
                                           + n0 + (row & 63)) * CC + slot * 16);
        }
        #pragma unroll
        for (int k = 0; k < 8; k++) {
            int id = (half * 8 + k) * 256 + tx;
            int row = id >> 4, slot = id & 15;
            *(uint4*)&Ls[row * 256 + ((slot ^ (row & 15)) << 4)] = st[k];
        }
    }
    __syncthreads();

    int4v acc[TT][2][2];
    #pragma unroll
    for (int t = 0; t < TT; t++)
    #pragma unroll
    for (int mi = 0; mi < 2; mi++)
    #pragma unroll
    for (int ni = 0; ni < 2; ni++) acc[t][mi][ni] = (int4v){0, 0, 0, 0};

    #pragma unroll
    for (int d = 0; d < 3; d++) {
        if (d > 0) {
            #pragma unroll
            for (int t = 0; t < TT; t++)
            #pragma unroll
            for (int mi = 0; mi < 2; mi++)
            #pragma unroll
            for (int ni = 0; ni < 2; ni++) acc[t][mi][ni] = acc[t][mi][ni] << 8;
        }
        #pragma unroll
        for (int ko = 0; ko < 4; ko++) {
            int4v wf[2];
            #pragma unroll
            for (int mi = 0; mi < 2; mi++) {
                size_t fb = ((((size_t)ht * 4 + ko) * 4 + (mh >> 4) + mi) << 10) + lane * 16;
                wf[mi] = *(const int4v*)(w1d + (size_t)d * 262144 + fb);
            }
            #pragma unroll
            for (int t = 0; t < TT; t++) {
                int4v sf0 = *(const int4v*)&Ls[(t * 64 + wn + ln) * 256
                                               + (((ko * 4 + q) ^ ln) << 4)];
                int4v sf1 = *(const int4v*)&Ls[(t * 64 + wn + 16 + ln) * 256
                                               + (((ko * 4 + q) ^ ln) << 4)];
                acc[t][0][0] = __builtin_amdgcn_mfma_i32_16x16x64_i8(wf[0], sf0, acc[t][0][0], 0, 0, 0);
                acc[t][0][1] = __builtin_amdgcn_mfma_i32_16x16x64_i8(wf[0], sf1, acc[t][0][1], 0, 0, 0);
                acc[t][1][0] = __builtin_amdgcn_mfma_i32_16x16x64_i8(wf[1], sf0, acc[t][1][0], 0, 0, 0);
                acc[t][1][1] = __builtin_amdgcn_mfma_i32_16x16x64_i8(wf[1], sf1, acc[t][1][1], 0, 0, 0);
            }
        }
    }

    // epilogue: exact integer -> f32 (*2^-24), bias + bn1 + LIF, packed stores
    #pragma unroll
    for (int mi = 0; mi < 2; mi++) {
        float invr[4], addr_[4], biasr[4];
        #pragma unroll
        for (int r = 0; r < 4; r++) {
            int h = h0 + mh + mi * 16 + q * 4 + r;
            float rsq = __fdiv_rn(1.0f, __fsqrt_rn(__fadd_rn(va1[h], 1e-5f)));
            invr[r] = __fmul_rn(g1[h], rsq);
            addr_[r] = __fsub_rn(be1[h], __fmul_rn(mu1[h], invr[r]));
            biasr[r] = b1[h];
        }
        #pragma unroll
        for (int ni = 0; ni < 2; ni++) {
            int l_n = n0 + wn + ni * 16 + ln;
            float v4[4] = {0.f, 0.f, 0.f, 0.f};
            #pragma unroll
            for (int t = 0; t < TT; t++) {
                unsigned int pk = 0;
                #pragma unroll
                for (int r = 0; r < 4; r++) {
                    float h1 = __fadd_rn(__fmul_rn((float)acc[t][mi][ni][r],
                                                   5.9604644775390625e-08f), biasr[r]); // 2^-24
                    float y  = __fadd_rn(__fmul_rn(h1, invr[r]), addr_[r]);
                    float vv = __fadd_rn(v4[r], __fdiv_rn(__fsub_rn(y, v4[r]), 1.5f));
                    bool sp = vv >= 1.0f;
                    v4[r] = sp ? 0.0f : vv;
                    if (sp) pk |= (1u << (8 * r));
                }
                *(unsigned int*)(s2T + ((size_t)bl * LLv + t * NNv + l_n) * HH
                                 + h0 + mh + mi * 16 + q * 4) = pk;
            }
        }
    }
}

// ------- GEMM2 (fc2) i8 2-digit with acc<<8 shift trick, fp32 out -------
// Tile 64l x 64c; ALL K=1024 staged once (64KB LDS, XOR-swizzled), one barrier;
// digit-major passes, exact integer combine.
__global__ __launch_bounds__(256, 3) void k_gemm2(
    const unsigned char* __restrict__ w2d,
    const float* __restrict__ b2c,
    const unsigned char* __restrict__ s2T, float* __restrict__ outp, int b0)
{
    __shared__ unsigned char Ls[64 * 1024];        // 64KB: [row=l(64)][slot64^swz]
    const int tx = threadIdx.x;
    const int l0 = blockIdx.x * 64;
    const int ct = blockIdx.y;
    const int bl = blockIdx.z;
    const int b  = b0 + bl;
    const int lane = tx & 63, w = tx >> 6;
    const int q = lane >> 4, ln = lane & 15;
    const int mc = (w & 1) * 32, wl = (w >> 1) * 32;

    // --- stage all K once: LDS[row][slot^(row&15)] = s2T[row][slot] ---
    #pragma unroll
    for (int half = 0; half < 2; half++) {
        uint4 st[8];
        #pragma unroll
        for (int k = 0; k < 8; k++) {
            int id = (half * 8 + k) * 256 + tx;
            int row = id >> 6, slot = id & 63;
            st[k] = *(const uint4*)(s2T + ((size_t)bl * LLv + l0 + row) * HH + slot * 16);
        }
        #pragma unroll
        for (int k = 0; k < 8; k++) {
            int id = (half * 8 + k) * 256 + tx;
            int row = id >> 6, slot = id & 63;
            *(uint4*)&Ls[row * 1024 + ((slot ^ (row & 15)) << 4)] = st[k];
        }
    }
    __syncthreads();

    int4v acc[2][2];
    #pragma unroll
    for (int mi = 0; mi < 2; mi++)
    #pragma unroll
    for (int ni = 0; ni < 2; ni++) acc[mi][ni] = (int4v){0, 0, 0, 0};

    #pragma unroll
    for (int d = 0; d < 2; d++) {
        if (d > 0) {
            #pragma unroll
            for (int mi = 0; mi < 2; mi++)
            #pragma unroll
            for (int ni = 0; ni < 2; ni++) acc[mi][ni] = acc[mi][ni] << 8;
        }
        #pragma unroll
        for (int ko = 0; ko < 16; ko++) {
            int4v wf[2];
            #pragma unroll
            for (int mi = 0; mi < 2; mi++) {
                size_t fb = ((((size_t)ct * 16 + ko) * 4 + (mc >> 4) + mi) << 10) + lane * 16;
                wf[mi] = *(const int4v*)(w2d + (size_t)d * 262144 + fb);
            }
            int4v sf0 = *(const int4v*)&Ls[(wl + ln) * 1024 + (((ko * 4 + q) ^ ln) << 4)];
            int4v sf1 = *(const int4v*)&Ls[(wl + 16 + ln) * 1024 + (((ko * 4 + q) ^ ln) << 4)];
            acc[0][0] = __builtin_amdgcn_mfma_i32_16x16x64_i8(wf[0], sf0, acc[0][0], 0, 0, 0);
            acc[0][1] = __builtin_amdgcn_mfma_i32_16x16x64_i8(wf[0], sf1, acc[0][1], 0, 0, 0);
            acc[1][0] = __builtin_amdgcn_mfma_i32_16x16x64_i8(wf[1], sf0, acc[1][0], 0, 0, 0);
            acc[1][1] = __builtin_amdgcn_mfma_i32_16x16x64_i8(wf[1], sf1, acc[1][1], 0, 0, 0);
        }
    }

    #pragma unroll
    for (int mi = 0; mi < 2; mi++)
    #pragma unroll
    for (int ni = 0; ni < 2; ni++) {
        #pragma unroll
        for (int r = 0; r < 4; r++) {
            int c = ct * 64 + mc + mi * 16 + q * 4 + r;
            int l = l0 + wl + ni * 16 + ln;
            outp[((size_t)b * CC + c) * LLv + l] =
                __fadd_rn(__fmul_rn((float)acc[mi][ni][r], 1.52587890625e-05f), b2c[c]); // 2^-16
        }
    }
}

extern "C" void kernel_launch(void* const* d_in, const int* in_sizes, int n_in,
                              void* d_out, int out_size, void* d_ws, size_t ws_size,
                              hipStream_t stream) {
    const float* x    = (const float*)d_in[0];
    const float* fc1w = (const float*)d_in[1];
    const float* fc1b = (const float*)d_in[2];
    const float* fc2w = (const float*)d_in[3];
    const float* fc2b = (const float*)d_in[4];
    const float* g1   = (const float*)d_in[5];
    const float* be1  = (const float*)d_in[6];
    const float* mu1  = (const float*)d_in[7];
    const float* va1  = (const float*)d_in[8];
    const float* g2   = (const float*)d_in[9];
    const float* be2  = (const float*)d_in[10];
    const float* mu2  = (const float*)d_in[11];
    const float* va2  = (const float*)d_in[12];

    // Workspace layout (ws_size-adaptive; NEVER exceed ws_size — overflow
    // clobbers adjacent input allocations and corrupts x on later calls):
    //   w1d: 3*262144 i8 digits (768 KB)
    //   w2d: 2*262144 i8 digits (512 KB)
    //   s1T: (full? 8 : 1) * 4 MB      bn2+LIF spike bytes [b][t][n][c]
    //   s2T: nbc * 16.78 MB            layer-1 spike bytes [bl][l][h]
    const size_t WB  = (size_t)3 * 262144 + (size_t)2 * 262144;          // 1,310,720
    const size_t S1B = (size_t)TT * NNv * CC;                            // 4,194,304 per b
    const size_t S2B = (size_t)LLv * HH;                                 // 16,777,216 per b

    int nbc;          // batch elements per gemm1/gemm2 chunk
    bool full_s1;     // s1T holds all 8 batches (bn2 runs once)?
    if      (ws_size >= WB + 8 * S1B + 8 * S2B) { nbc = 8; full_s1 = true;  }
    else if (ws_size >= WB + 8 * S1B + 4 * S2B) { nbc = 4; full_s1 = true;  }
    else if (ws_size >= WB + 8 * S1B + 2 * S2B) { nbc = 2; full_s1 = true;  }
    else if (ws_size >= WB + 8 * S1B + 1 * S2B) { nbc = 1; full_s1 = true;  }
    else                                        { nbc = 1; full_s1 = false; }

    unsigned char* w1d = (unsigned char*)d_ws;
    unsigned char* w2d = w1d + (size_t)3 * 262144;
    unsigned char* s1T = w2d + (size_t)2 * 262144;
    unsigned char* s2T = s1T + (full_s1 ? (size_t)8 * S1B : S1B);
    float* outp = (float*)d_out;

    hipLaunchKernelGGL(k_prep1, dim3(1024), dim3(256), 0, stream, fc1w, w1d);
    hipLaunchKernelGGL(k_prep2, dim3(1024), dim3(256), 0, stream, fc2w, w2d);

    if (full_s1) {
        hipLaunchKernelGGL(k_bn2_lif_t, dim3(NNv / 64, CC / 64, BB), dim3(256), 0, stream,
                           x, g2, be2, mu2, va2, s1T, 0);
        for (int b0 = 0; b0 < BB; b0 += nbc) {
            hipLaunchKernelGGL(k_gemm1_lif, dim3(NNv / 64, HH / 64, nbc), dim3(256), 0, stream,
                               w1d, fc1b, g1, be1, mu1, va1, s1T + (size_t)b0 * S1B, s2T);
            hipLaunchKernelGGL(k_gemm2, dim3(LLv / 64, CC / 64, nbc), dim3(256), 0, stream,
                               w2d, fc2b, s2T, outp, b0);
        }
    } else {
        for (int b0 = 0; b0 < BB; ++b0) {
            hipLaunchKernelGGL(k_bn2_lif_t, dim3(NNv / 64, CC / 64, 1), dim3(256), 0, stream,
                               x, g2, be2, mu2, va2, s1T, b0);
            hipLaunchKernelGGL(k_gemm1_lif, dim3(NNv / 64, HH / 64, 1), dim3(256), 0, stream,
                               w1d, fc1b, g1, be1, mu1, va1, s1T, s2T);
            hipLaunchKernelGGL(k_gemm2, dim3(LLv / 64, CC / 64, 1), dim3(256), 0, stream,
                               w2d, fc2b, s2T, outp, b0);
        }
    }
}

// Round 7
// 597.183 us; speedup vs baseline: 1.1143x; 1.1143x over previous
//
#include <hip/hip_runtime.h>

#define BB 8
#define CC 256
#define TT 4
#define NNv 4096
#define HH 1024
#define LLv (TT*NNv)   // 16384

typedef short bf16x8 __attribute__((ext_vector_type(8)));
typedef float f32x4 __attribute__((ext_vector_type(4)));

static __device__ __forceinline__ float bfbits2f(unsigned short h) {
    return __uint_as_float(((unsigned int)h) << 16);
}
static __device__ __forceinline__ unsigned short f2bf(float f) {
    unsigned int u = __float_as_uint(f);
    return (unsigned short)((u + 0x7FFFu + ((u >> 16) & 1u)) >> 16);
}
// byte j of a group-of-8 lands at fragment slot p = permpos(j); the spike
// expansion below emits source bytes in order {0,2,4,6,1,3,5,7} at slots 0..7.
static __device__ __forceinline__ int permpos(int j) { return (j >> 1) + ((j & 1) << 2); }

// byte->bf16 {0,1}: slot p holds source byte perm[p], perm = {0,2,4,6,1,3,5,7}
static __device__ __forceinline__ uint4 spikes8_to_bf16(unsigned long long d) {
    unsigned int lo = (unsigned int)d, hi = (unsigned int)(d >> 32);
    uint4 o;
    o.x = (lo & 0x10001u) * 0x3F80u;
    o.y = (hi & 0x10001u) * 0x3F80u;
    o.z = ((lo >> 8) & 0x10001u) * 0x3F80u;
    o.w = ((hi >> 8) & 0x10001u) * 0x3F80u;
    return o;
}

// Barrier that does NOT drain vmcnt: LDS ops flushed (lgkmcnt), prefetch
// global loads stay in flight across the barrier. sched_barrier(0) pins
// post-barrier ds ops below the s_barrier (rule #18).
static __device__ __forceinline__ void barrier_keep_vmem() {
    asm volatile("s_waitcnt lgkmcnt(0)" ::: "memory");
    __builtin_amdgcn_s_barrier();
    __builtin_amdgcn_sched_barrier(0);
}

// ---- fc1 weights -> fragment-linear 3-split (hi/mid/lo), k-permuted ----
// dst: ((((ht*4+ko)*2+kb)*4+g)*64 + q*16+ln)*8 + p   (+ s*262144)
__global__ __launch_bounds__(256) void k_prep1(const float* __restrict__ w,
                                               unsigned short* __restrict__ wf)
{
    int i = blockIdx.x * 256 + threadIdx.x;        // i = h*256 + c
    int h = i >> 8, c = i & 255;
    int ht = h >> 6, hr = h & 63, g = hr >> 4, ln = hr & 15;
    int ko = c >> 6, cr = c & 63, kb = cr >> 5, q = (cr >> 3) & 3, j = c & 7;
    size_t base = (((((size_t)ht * 4 + ko) * 2 + kb) * 4 + g) * 64 + q * 16 + ln) * 8 + permpos(j);
    const size_t WS = 262144;
    float x = w[i];
    unsigned short hi = f2bf(x); float r  = __fsub_rn(x, bfbits2f(hi));
    unsigned short md = f2bf(r); float r2 = __fsub_rn(r, bfbits2f(md));
    unsigned short lo = f2bf(r2);
    wf[base] = hi; wf[WS + base] = md; wf[2 * WS + base] = lo;
}

// ---- fc2 weights -> fragment-linear 2-split (hi/lo), k-permuted ----
// dst: ((((ct*8+ko)*4+kb)*4+g)*64 + q*16+ln)*8 + p   (+ s*262144)
__global__ __launch_bounds__(256) void k_prep2(const float* __restrict__ w,
                                               unsigned short* __restrict__ wf)
{
    int i = blockIdx.x * 256 + threadIdx.x;        // i = c*1024 + h
    int c = i >> 10, h = i & 1023;
    int ct = c >> 6, cr = c & 63, g = cr >> 4, ln = cr & 15;
    int ko = h >> 7, hr = h & 127, kb = hr >> 5, q = (hr >> 3) & 3, j = h & 7;
    size_t base = (((((size_t)ct * 8 + ko) * 4 + kb) * 4 + g) * 64 + q * 16 + ln) * 8 + permpos(j);
    const size_t WS = 262144;
    float x = w[i];
    unsigned short hi = f2bf(x); float r = __fsub_rn(x, bfbits2f(hi));
    unsigned short lo = f2bf(r);
    wf[base] = hi; wf[WS + base] = lo;
}

// ---- bn2 + LIF over T + transpose: x[b][c][t][n] -> s1T[bl][t][n][c] bytes ----
__global__ __launch_bounds__(256) void k_bn2_lif_t(
    const float* __restrict__ x,
    const float* __restrict__ g, const float* __restrict__ be,
    const float* __restrict__ mu, const float* __restrict__ va,
    unsigned char* __restrict__ s1T, int b0)
{
    __shared__ unsigned char ts[TT][64][80];       // [t][c][n], stride 80 (16B-aligned)
    int tx = threadIdx.x;
    int n0 = blockIdx.x * 64;
    int c0 = blockIdx.y * 64;
    int bl = blockIdx.z;
    int b  = b0 + bl;
    int cl = tx >> 2, np = tx & 3;
    int c = c0 + cl;
    float rsq = __fdiv_rn(1.0f, __fsqrt_rn(__fadd_rn(va[c], 1e-5f)));
    float inv = __fmul_rn(g[c], rsq);
    float add = __fsub_rn(be[c], __fmul_rn(mu[c], inv));
    size_t xb = ((size_t)(b * CC + c) * TT) * NNv + n0 + np * 16;
    float v[16];
    #pragma unroll
    for (int i = 0; i < 16; i++) v[i] = 0.0f;
    #pragma unroll
    for (int t = 0; t < TT; t++) {
        float4 p[4];
        #pragma unroll
        for (int k = 0; k < 4; k++) p[k] = *(const float4*)(x + xb + (size_t)t * NNv + 4 * k);
        const float* xp = (const float*)p;
        unsigned int ob[4] = {0, 0, 0, 0};
        #pragma unroll
        for (int i = 0; i < 16; i++) {
            float y = __fadd_rn(__fmul_rn(xp[i], inv), add);
            float vv = __fadd_rn(v[i], __fdiv_rn(__fsub_rn(y, v[i]), 1.5f));
            bool sp = vv >= 1.0f;
            v[i] = sp ? 0.0f : vv;
            if (sp) ob[i >> 2] |= 1u << (8 * (i & 3));
        }
        uint4 pk; pk.x = ob[0]; pk.y = ob[1]; pk.z = ob[2]; pk.w = ob[3];
        *(uint4*)&ts[t][cl][np * 16] = pk;
    }
    __syncthreads();
    int nl = tx >> 2, cp = tx & 3;
    #pragma unroll
    for (int t = 0; t < TT; t++) {
        unsigned int u[4];
        #pragma unroll
        for (int kk = 0; kk < 4; kk++) {
            u[kk] = (unsigned int)ts[t][cp * 16 + kk * 4 + 0][nl]
                  | ((unsigned int)ts[t][cp * 16 + kk * 4 + 1][nl] << 8)
                  | ((unsigned int)ts[t][cp * 16 + kk * 4 + 2][nl] << 16)
                  | ((unsigned int)ts[t][cp * 16 + kk * 4 + 3][nl] << 24);
        }
        uint4 pk; pk.x = u[0]; pk.y = u[1]; pk.z = u[2]; pk.w = u[3];
        *(uint4*)(s1T + ((size_t)(bl * TT + t) * NNv + n0 + nl) * CC + c0 + cp * 16) = pk;
    }
}

// ------- GEMM1 (fc1) bf16 3-split, single-buffer LDS + reg prefetch, bn1+LIF -------
// launch_bounds(256,3): total regs capped ~170 (R1 needed 104 arch + 64 acc = 168)
// -> 3 waves/SIMD. Single 36.9KB LDS buffer keeps blocks/CU un-capped by LDS.
// Both barriers are lgkm-only so prefetch vmem stays in flight.
__global__ __launch_bounds__(256, 3) void k_gemm1_lif(
    const unsigned short* __restrict__ w1f,
    const float* __restrict__ b1,
    const float* __restrict__ g1, const float* __restrict__ be1,
    const float* __restrict__ mu1, const float* __restrict__ va1,
    const unsigned char* __restrict__ s1T, unsigned char* __restrict__ s2T)
{
    __shared__ unsigned short Ss[TT][64][72];      // 36,864 B
    const int tx = threadIdx.x;
    const int n0 = blockIdx.x * 64;
    const int ht = blockIdx.y;
    const int bl = blockIdx.z;
    const int lane = tx & 63, w = tx >> 6;
    const int q = lane >> 4, ln = lane & 15;
    const int mh = (w & 1) * 32, wn = (w >> 1) * 32;
    const int h0 = ht * 64;
    const size_t WS = 262144;

    f32x4 acc[TT][2][2];
    #pragma unroll
    for (int t = 0; t < TT; t++)
    #pragma unroll
    for (int mi = 0; mi < 2; mi++)
    #pragma unroll
    for (int ni = 0; ni < 2; ni++)
        acc[t][mi][ni] = (f32x4){0.f, 0.f, 0.f, 0.f};

    unsigned long long d[2][8];
    #pragma unroll
    for (int i = 0; i < 8; i++) {
        int task = i * 256 + tx;
        int cb = task & 7, nr = (task >> 3) & 63, t = task >> 9;
        d[0][i] = *(const unsigned long long*)(
            s1T + ((size_t)(bl * TT + t) * NNv + n0 + nr) * CC + 0 * 64 + cb * 8);
    }

    #pragma unroll
    for (int ko = 0; ko < 4; ko++) {
        const int cur = ko & 1;
        // protect LDS overwrite: all waves' ds_reads of the previous tile have
        // completed into registers (lgkmcnt(0) inside barrier_keep_vmem)
        if (ko > 0) barrier_keep_vmem();
        #pragma unroll
        for (int i = 0; i < 8; i++) {
            int task = i * 256 + tx;
            int cb = task & 7, nr = (task >> 3) & 63, t = task >> 9;
            *(uint4*)&Ss[t][nr][cb * 8] = spikes8_to_bf16(d[cur][i]);
        }
        // issue next K-step's global loads; they stay in flight across barriers
        if (ko < 3) {
            #pragma unroll
            for (int i = 0; i < 8; i++) {
                int task = i * 256 + tx;
                int cb = task & 7, nr = (task >> 3) & 63, t = task >> 9;
                d[cur ^ 1][i] = *(const unsigned long long*)(
                    s1T + ((size_t)(bl * TT + t) * NNv + n0 + nr) * CC + (ko + 1) * 64 + cb * 8);
            }
        }
        barrier_keep_vmem();

        #pragma unroll
        for (int kb = 0; kb < 2; kb++) {
            bf16x8 wf[2][3];
            #pragma unroll
            for (int mi = 0; mi < 2; mi++) {
                int gg = (mh >> 4) + mi;
                size_t fbase = (((((size_t)ht * 4 + ko) * 2 + kb) * 4 + gg) * 64 + lane) * 8;
                #pragma unroll
                for (int s = 0; s < 3; s++)
                    wf[mi][s] = *(const bf16x8*)(w1f + s * WS + fbase);
            }
            #pragma unroll
            for (int t = 0; t < TT; t++) {
                bf16x8 sf0 = *(const bf16x8*)&Ss[t][wn + ln][kb * 32 + q * 8];
                bf16x8 sf1 = *(const bf16x8*)&Ss[t][wn + 16 + ln][kb * 32 + q * 8];
                #pragma unroll
                for (int s = 0; s < 3; s++) {
                    acc[t][0][0] = __builtin_amdgcn_mfma_f32_16x16x32_bf16(wf[0][s], sf0, acc[t][0][0], 0, 0, 0);
                    acc[t][0][1] = __builtin_amdgcn_mfma_f32_16x16x32_bf16(wf[0][s], sf1, acc[t][0][1], 0, 0, 0);
                    acc[t][1][0] = __builtin_amdgcn_mfma_f32_16x16x32_bf16(wf[1][s], sf0, acc[t][1][0], 0, 0, 0);
                    acc[t][1][1] = __builtin_amdgcn_mfma_f32_16x16x32_bf16(wf[1][s], sf1, acc[t][1][1], 0, 0, 0);
                }
            }
        }
    }

    // epilogue: bias + bn1 + LIF scan over t; packed 4-byte spike stores to s2T[bl][l][h]
    #pragma unroll
    for (int mi = 0; mi < 2; mi++) {
        float invr[4], addr_[4], biasr[4];
        #pragma unroll
        for (int r = 0; r < 4; r++) {
            int h = h0 + mh + mi * 16 + q * 4 + r;
            float rsq = __fdiv_rn(1.0f, __fsqrt_rn(__fadd_rn(va1[h], 1e-5f)));
            invr[r] = __fmul_rn(g1[h], rsq);
            addr_[r] = __fsub_rn(be1[h], __fmul_rn(mu1[h], invr[r]));
            biasr[r] = b1[h];
        }
        #pragma unroll
        for (int ni = 0; ni < 2; ni++) {
            int l_n = n0 + wn + ni * 16 + ln;
            float v4[4] = {0.f, 0.f, 0.f, 0.f};
            #pragma unroll
            for (int t = 0; t < TT; t++) {
                unsigned int pk = 0;
                #pragma unroll
                for (int r = 0; r < 4; r++) {
                    float h1 = __fadd_rn(acc[t][mi][ni][r], biasr[r]);
                    float y  = __fadd_rn(__fmul_rn(h1, invr[r]), addr_[r]);
                    float vv = __fadd_rn(v4[r], __fdiv_rn(__fsub_rn(y, v4[r]), 1.5f));
                    bool sp = vv >= 1.0f;
                    v4[r] = sp ? 0.0f : vv;
                    if (sp) pk |= (1u << (8 * r));
                }
                *(unsigned int*)(s2T + ((size_t)bl * LLv + t * NNv + l_n) * HH
                                 + h0 + mh + mi * 16 + q * 4) = pk;
            }
        }
    }
}

// ------- GEMM2 (fc2) bf16 2-split, single-buffer LDS + reg prefetch, fp32 out -------
__global__ __launch_bounds__(256, 3) void k_gemm2(
    const unsigned short* __restrict__ w2f,
    const float* __restrict__ b2c,
    const unsigned char* __restrict__ s2T, float* __restrict__ outp, int b0)
{
    __shared__ unsigned short Ss[128][136];        // 34,816 B
    const int tx = threadIdx.x;
    const int l0 = blockIdx.x * 128;
    const int ct = blockIdx.y;
    const int bl = blockIdx.z;
    const int b  = b0 + bl;
    const int lane = tx & 63, w = tx >> 6;
    const int q = lane >> 4, ln = lane & 15;
    const int mc = (w & 1) * 32, wl = (w >> 1) * 64;
    const size_t WS = 262144;

    f32x4 acc[2][4];
    #pragma unroll
    for (int mi = 0; mi < 2; mi++)
    #pragma unroll
    for (int ni = 0; ni < 4; ni++)
        acc[mi][ni] = (f32x4){0.f, 0.f, 0.f, 0.f};

    unsigned long long d[2][8];
    #pragma unroll
    for (int i = 0; i < 8; i++) {
        int task = i * 256 + tx;
        int hb = task & 15, lr = task >> 4;
        d[0][i] = *(const unsigned long long*)(
            s2T + ((size_t)bl * LLv + l0 + lr) * HH + 0 * 128 + hb * 8);
    }

    #pragma unroll
    for (int ko = 0; ko < 8; ko++) {
        const int cur = ko & 1;
        if (ko > 0) barrier_keep_vmem();
        #pragma unroll
        for (int i = 0; i < 8; i++) {
            int task = i * 256 + tx;
            int hb = task & 15, lr = task >> 4;
            *(uint4*)&Ss[lr][hb * 8] = spikes8_to_bf16(d[cur][i]);
        }
        if (ko < 7) {
            #pragma unroll
            for (int i = 0; i < 8; i++) {
                int task = i * 256 + tx;
                int hb = task & 15, lr = task >> 4;
                d[cur ^ 1][i] = *(const unsigned long long*)(
                    s2T + ((size_t)bl * LLv + l0 + lr) * HH + (ko + 1) * 128 + hb * 8);
            }
        }
        barrier_keep_vmem();

        #pragma unroll
        for (int kb = 0; kb < 4; kb++) {
            bf16x8 wf[2][2];
            #pragma unroll
            for (int mi = 0; mi < 2; mi++) {
                int gg = (mc >> 4) + mi;
                size_t fbase = (((((size_t)ct * 8 + ko) * 4 + kb) * 4 + gg) * 64 + lane) * 8;
                #pragma unroll
                for (int s = 0; s < 2; s++)
                    wf[mi][s] = *(const bf16x8*)(w2f + s * WS + fbase);
            }
            bf16x8 sf[4];
            #pragma unroll
            for (int ni = 0; ni < 4; ni++)
                sf[ni] = *(const bf16x8*)&Ss[wl + ni * 16 + ln][kb * 32 + q * 8];
            #pragma unroll
            for (int s = 0; s < 2; s++)
            #pragma unroll
            for (int mi = 0; mi < 2; mi++)
            #pragma unroll
            for (int ni = 0; ni < 4; ni++)
                acc[mi][ni] = __builtin_amdgcn_mfma_f32_16x16x32_bf16(wf[mi][s], sf[ni], acc[mi][ni], 0, 0, 0);
        }
    }
    #pragma unroll
    for (int mi = 0; mi < 2; mi++)
    #pragma unroll
    for (int r = 0; r < 4; r++) {
        int c = ct * 64 + mc + mi * 16 + q * 4 + r;
        float bias = b2c[c];
        #pragma unroll
        for (int ni = 0; ni < 4; ni++) {
            int l = l0 + wl + ni * 16 + ln;
            outp[((size_t)b * CC + c) * LLv + l] = __fadd_rn(acc[mi][ni][r], bias);
        }
    }
}

extern "C" void kernel_launch(void* const* d_in, const int* in_sizes, int n_in,
                              void* d_out, int out_size, void* d_ws, size_t ws_size,
                              hipStream_t stream) {
    const float* x    = (const float*)d_in[0];
    const float* fc1w = (const float*)d_in[1];
    const float* fc1b = (const float*)d_in[2];
    const float* fc2w = (const float*)d_in[3];
    const float* fc2b = (const float*)d_in[4];
    const float* g1   = (const float*)d_in[5];
    const float* be1  = (const float*)d_in[6];
    const float* mu1  = (const float*)d_in[7];
    const float* va1  = (const float*)d_in[8];
    const float* g2   = (const float*)d_in[9];
    const float* be2  = (const float*)d_in[10];
    const float* mu2  = (const float*)d_in[11];
    const float* va2  = (const float*)d_in[12];

    // Workspace layout (ws_size-adaptive; NEVER exceed ws_size — overflow
    // clobbers adjacent input allocations and corrupts x on later calls):
    //   w1f: 3*262144 shorts (1.5 MB)   fc1 weight fragments
    //   w2f: 2*262144 shorts (1.0 MB)   fc2 weight fragments
    //   s1T: (full? 8 : 1) * 4 MB       bn2+LIF spike bytes [b][t][n][c]
    //   s2T: nbc * 16.78 MB             layer-1 spike bytes [bl][l][h]
    const size_t WB  = (size_t)(3 + 2) * 262144 * sizeof(unsigned short); // 2,621,440
    const size_t S1B = (size_t)TT * NNv * CC;                             // 4,194,304 per b
    const size_t S2B = (size_t)LLv * HH;                                  // 16,777,216 per b

    int nbc;          // batch elements per gemm1/gemm2 chunk
    bool full_s1;     // s1T holds all 8 batches (bn2 runs once)?
    if      (ws_size >= WB + 8 * S1B + 8 * S2B) { nbc = 8; full_s1 = true;  }
    else if (ws_size >= WB + 8 * S1B + 4 * S2B) { nbc = 4; full_s1 = true;  }
    else if (ws_size >= WB + 8 * S1B + 2 * S2B) { nbc = 2; full_s1 = true;  }
    else if (ws_size >= WB + 8 * S1B + 1 * S2B) { nbc = 1; full_s1 = true;  }
    else                                        { nbc = 1; full_s1 = false; }

    unsigned short* w1f = (unsigned short*)d_ws;                        // 3*262144 shorts
    unsigned short* w2f = w1f + (size_t)3 * 262144;                     // 2*262144 shorts
    unsigned char*  s1T = (unsigned char*)(w2f + (size_t)2 * 262144);
    unsigned char*  s2T = s1T + (full_s1 ? (size_t)8 * S1B : S1B);
    float* outp = (float*)d_out;

    hipLaunchKernelGGL(k_prep1, dim3(1024), dim3(256), 0, stream, fc1w, w1f);
    hipLaunchKernelGGL(k_prep2, dim3(1024), dim3(256), 0, stream, fc2w, w2f);

    if (full_s1) {
        hipLaunchKernelGGL(k_bn2_lif_t, dim3(NNv / 64, CC / 64, BB), dim3(256), 0, stream,
                           x, g2, be2, mu2, va2, s1T, 0);
        for (int b0 = 0; b0 < BB; b0 += nbc) {
            hipLaunchKernelGGL(k_gemm1_lif, dim3(NNv / 64, HH / 64, nbc), dim3(256), 0, stream,
                               w1f, fc1b, g1, be1, mu1, va1, s1T + (size_t)b0 * S1B, s2T);
            hipLaunchKernelGGL(k_gemm2, dim3(LLv / 128, CC / 64, nbc), dim3(256), 0, stream,
                               w2f, fc2b, s2T, outp, b0);
        }
    } else {
        for (int b0 = 0; b0 < BB; ++b0) {
            hipLaunchKernelGGL(k_bn2_lif_t, dim3(NNv / 64, CC / 64, 1), dim3(256), 0, stream,
                               x, g2, be2, mu2, va2, s1T, b0);
            hipLaunchKernelGGL(k_gemm1_lif, dim3(NNv / 64, HH / 64, 1), dim3(256), 0, stream,
                               w1f, fc1b, g1, be1, mu1, va1, s1T, s2T);
            hipLaunchKernelGGL(k_gemm2, dim3(LLv / 128, CC / 64, 1), dim3(256), 0, stream,
                               w2f, fc2b, s2T, outp, b0);
        }
    }
}